// Round 1
// baseline (201.968 us; speedup 1.0000x reference)
//
#include <hip/hip_runtime.h>

typedef __attribute__((ext_vector_type(8))) __bf16 bf16x8;
typedef __attribute__((ext_vector_type(4))) __bf16 bf16x4;
typedef __attribute__((ext_vector_type(4))) float  f32x4;

static constexpr int TSEQ    = 2048;
static constexpr int DMODEL  = 1024;
static constexpr int HD      = 64;
static constexpr int VSTRIDE = 2080;   // V^T row stride (breaks 4KB L2-channel aliasing)

#define AS1 __attribute__((address_space(1)))
#define AS3 __attribute__((address_space(3)))
// XOR bank swizzle on 16B chunks within a 128B row: distinct slots for rows r, r+4, r+8, r+12
#define SW(r) ((((r) >> 3) ^ (r)) & 7)

// ---------------- fused preprocessing: convert x + transpose weights ----------------
__global__ __launch_bounds__(256) void k_prep(const float* __restrict__ x,
    const float* __restrict__ w0, const float* __restrict__ w1,
    const float* __restrict__ w2, const float* __restrict__ w3,
    __bf16* __restrict__ xbf, __bf16* __restrict__ wt_all) {
  __shared__ float tile[32][33];
  const int blk = blockIdx.x;
  const int tid = threadIdx.x;
  if (blk < 4096) {
    size_t i = ((size_t)blk * 256 + tid) * 4;
    float4 v = *(const float4*)(x + i);
    bf16x4 o = { (__bf16)v.x, (__bf16)v.y, (__bf16)v.z, (__bf16)v.w };
    *(bf16x4*)(xbf + i) = o;
    return;
  }
  const int tz = blk - 4096;
  const int wi = tz >> 10;                 // which weight
  const int tl = tz & 1023;
  const int n0 = (tl & 31) * 32, k0 = (tl >> 5) * 32;
  const float* w = wi == 0 ? w0 : wi == 1 ? w1 : wi == 2 ? w2 : w3;
  __bf16* out = wt_all + (size_t)wi * DMODEL * DMODEL;
  const int tx = tid & 31, ty0 = (tid >> 5) * 4;
#pragma unroll
  for (int j = 0; j < 4; j++)
    tile[ty0 + j][tx] = w[(size_t)(k0 + ty0 + j) * DMODEL + n0 + tx];
  __syncthreads();
#pragma unroll
  for (int j = 0; j < 4; j++)
    out[(size_t)(n0 + ty0 + j) * DMODEL + k0 + tx] = (__bf16)tile[tx][ty0 + j];
}

// ---------------- m97-style GEMM mainloop (R6): global_load_lds width-16, BK=32 ----------------
__device__ __forceinline__ void gemm_mainloop(const __bf16* __restrict__ A,
                                              const __bf16* __restrict__ Bt,
                                              int bm, int bn,
                                              __bf16* At, __bf16* Bl,
                                              f32x4 acc[4][4]) {
  const int tid  = threadIdx.x;
  const int lane = tid & 63;
  const int l15  = lane & 15, quad = lane >> 4;
  const int wv   = tid >> 6;
  const int wm   = (wv >> 1) * 64, wn = (wv & 1) * 64;
  const int s0   = wv * 2;
  const int srow = lane >> 2;
  const int scol = (lane & 3) << 3;
  for (int k0 = 0; k0 < 1024; k0 += 32) {
    __syncthreads();
#pragma unroll
    for (int ss = 0; ss < 2; ss++) {
      const int s   = s0 + ss;
      const int row = s * 16 + srow;
      const __bf16* ga = A  + (size_t)(bm + row) * 1024 + k0 + scol;
      const __bf16* gb = Bt + (size_t)(bn + row) * 1024 + k0 + scol;
      __builtin_amdgcn_global_load_lds((const AS1 void*)ga,
                                       (AS3 void*)(At + s * 512), 16, 0, 0);
      __builtin_amdgcn_global_load_lds((const AS1 void*)gb,
                                       (AS3 void*)(Bl + s * 512), 16, 0, 0);
    }
    __syncthreads();
    bf16x8 af[4], bfr[4];
#pragma unroll
    for (int mt = 0; mt < 4; mt++)
      af[mt] = *(const bf16x8*)(At + (wm + mt * 16 + l15) * 32 + quad * 8);
#pragma unroll
    for (int nt = 0; nt < 4; nt++)
      bfr[nt] = *(const bf16x8*)(Bl + (wn + nt * 16 + l15) * 32 + quad * 8);
#pragma unroll
    for (int mt = 0; mt < 4; mt++)
#pragma unroll
      for (int nt = 0; nt < 4; nt++)
        acc[mt][nt] = __builtin_amdgcn_mfma_f32_16x16x32_bf16(
            af[mt], bfr[nt], acc[mt][nt], 0, 0, 0);
  }
}

// ---------------- QKV projection (Q pre-scaled by log2e/8; V stored transposed) ----------------
__global__ __launch_bounds__(256) void k_gemm_qkv(const __bf16* __restrict__ xbf,
    const __bf16* __restrict__ wt_all, __bf16* __restrict__ qws,
    __bf16* __restrict__ kws, __bf16* __restrict__ vtws) {
  __shared__ __bf16 At[128 * 32];
  __shared__ __bf16 Bl[128 * 32];
  const int which = blockIdx.z;
  const __bf16* wt = wt_all + (size_t)which * DMODEL * DMODEL;
  const int bm = blockIdx.y * 128, bn = blockIdx.x * 128;
  f32x4 acc[4][4];
  const f32x4 z = {0.f, 0.f, 0.f, 0.f};
#pragma unroll
  for (int mt = 0; mt < 4; mt++)
#pragma unroll
    for (int nt = 0; nt < 4; nt++) acc[mt][nt] = z;
  gemm_mainloop(xbf, wt, bm, bn, At, Bl, acc);
  const int lane = threadIdx.x & 63;
  const int l15 = lane & 15, quad = lane >> 4;
  const int wv = threadIdx.x >> 6;
  const int wm = (wv >> 1) * 64, wn = (wv & 1) * 64;
#pragma unroll
  for (int mt = 0; mt < 4; mt++)
#pragma unroll
    for (int nt = 0; nt < 4; nt++)
#pragma unroll
      for (int r = 0; r < 4; r++) {
        int m = bm + wm + mt * 16 + quad * 4 + r;
        int n = bn + wn + nt * 16 + l15;
        int b = m >> 11, t = m & 2047;
        int h = n >> 6,  d = n & 63;
        int bh = b * 16 + h;
        float av = acc[mt][nt][r];
        // 0.125 * log2(e): lets attention use v_exp_f32 (exp2) directly
        if (which == 0)      qws[((size_t)bh * TSEQ + t) * HD + d] = (__bf16)(av * 0.18033688f);
        else if (which == 1) kws[((size_t)bh * TSEQ + t) * HD + d] = (__bf16)av;
        else                 vtws[((size_t)bh * HD + d) * VSTRIDE + t] = (__bf16)av;
      }
}

// ---------------- flash attention (R7): single 128-row stream per block, 32 q-rows/wave,
// XOR-swizzled unpadded LDS tiles, exp2, causal step-count with balanced pairing ----------------
// grid 512: bh = blk & 31 (XCD locality: 4 bh/XCD => 2MB K+V L2-resident).
// tr = blk>>5 maps to stream a s.t. co-resident pairs (blk, blk+256) sum to 34 steps.
__global__ __launch_bounds__(256) void k_attn(const __bf16* __restrict__ qws,
    const __bf16* __restrict__ kws, const __bf16* __restrict__ vtws,
    __bf16* __restrict__ ctx) {
  const int bh = blockIdx.x & 31;
  const int tr = blockIdx.x >> 5;                      // 0..15
  const int a  = (tr < 8) ? (2 * tr) : (2 * (15 - tr) + 1);  // stream index 0..15
  const int tcnt = 2 * a + 2;                          // causal K-tile count
  const int tid = threadIdx.x;
  const int lane = tid & 63, wv = tid >> 6;
  const int l15 = lane & 15, quad = lane >> 4;
  const __bf16* qp = qws  + (size_t)bh * TSEQ * HD;
  const __bf16* kp = kws  + (size_t)bh * TSEQ * HD;
  const __bf16* vp = vtws + (size_t)bh * HD * VSTRIDE;
  const int b = bh >> 4, h = bh & 15;
  const int qbase = a * 128 + wv * 32;                 // this wave's first q-row

  __shared__ __align__(16) __bf16 kbuf[2][64 * 64];
  __shared__ __align__(16) __bf16 vbuf[2][64 * 64];
  __shared__ __align__(16) __bf16 plds[4][32 * 64];

  const int sr = tid >> 3;        // staging row 0..31
  const int c8 = tid & 7;         // staging 16B chunk

  // Q fragments: 32 rows per wave = 2 m-tiles, K=64 feat = 2 kb chunks
  bf16x8 aq[2][2];
#pragma unroll
  for (int mt = 0; mt < 2; mt++)
#pragma unroll
    for (int kb = 0; kb < 2; kb++)
      aq[mt][kb] = *(const bf16x8*)(qp + (size_t)(qbase + mt * 16 + l15) * HD + kb * 32 + quad * 8);

  // stage tile 0 (swizzled reg->LDS)
  bf16x8 kreg[2], vreg[2];
  kreg[0] = *(const bf16x8*)(kp + (size_t)sr * HD + c8 * 8);
  kreg[1] = *(const bf16x8*)(kp + (size_t)(sr + 32) * HD + c8 * 8);
  vreg[0] = *(const bf16x8*)(vp + (size_t)sr * VSTRIDE + c8 * 8);
  vreg[1] = *(const bf16x8*)(vp + (size_t)(sr + 32) * VSTRIDE + c8 * 8);
  *(bf16x8*)(kbuf[0] + sr * 64 + ((c8 ^ SW(sr)) << 3))             = kreg[0];
  *(bf16x8*)(kbuf[0] + (sr + 32) * 64 + ((c8 ^ SW(sr + 32)) << 3)) = kreg[1];
  *(bf16x8*)(vbuf[0] + sr * 64 + ((c8 ^ SW(sr)) << 3))             = vreg[0];
  *(bf16x8*)(vbuf[0] + (sr + 32) * 64 + ((c8 ^ SW(sr + 32)) << 3)) = vreg[1];
  __syncthreads();

  float lpart[2][4] = {{0.f, 0.f, 0.f, 0.f}, {0.f, 0.f, 0.f, 0.f}};
  const f32x4 z = {0.f, 0.f, 0.f, 0.f};
  f32x4 acc[2][4];
#pragma unroll
  for (int mt = 0; mt < 2; mt++)
#pragma unroll
    for (int dt = 0; dt < 4; dt++) acc[mt][dt] = z;

  for (int t = 0; t < tcnt; t++) {
    const int cur = t & 1;
    if (t + 1 < tcnt) {                       // prefetch next tile into regs (hidden under compute)
      const int ktn = (t + 1) * 64;
      kreg[0] = *(const bf16x8*)(kp + (size_t)(ktn + sr) * HD + c8 * 8);
      kreg[1] = *(const bf16x8*)(kp + (size_t)(ktn + sr + 32) * HD + c8 * 8);
      vreg[0] = *(const bf16x8*)(vp + (size_t)sr * VSTRIDE + ktn + c8 * 8);
      vreg[1] = *(const bf16x8*)(vp + (size_t)(sr + 32) * VSTRIDE + ktn + c8 * 8);
    }

    const bool skipall = (t * 64) > (qbase + 31);     // wave fully above causal boundary
    if (!skipall) {
      const bool full = (t * 64 + 63) <= qbase;       // wave fully unmasked (wave-uniform)
      f32x4 sarr[2][4];
#pragma unroll
      for (int mt = 0; mt < 2; mt++)
#pragma unroll
        for (int nt = 0; nt < 4; nt++) sarr[mt][nt] = z;
#pragma unroll
      for (int kb = 0; kb < 2; kb++)
#pragma unroll
        for (int nt = 0; nt < 4; nt++) {
          const int row = nt * 16 + l15;
          bf16x8 bk = *(const bf16x8*)(kbuf[cur] + row * 64 + (((kb * 4 + quad) ^ SW(row)) << 3));
#pragma unroll
          for (int mt = 0; mt < 2; mt++)
            sarr[mt][nt] = __builtin_amdgcn_mfma_f32_16x16x32_bf16(aq[mt][kb], bk, sarr[mt][nt], 0, 0, 0);
        }
      if (full) {
#pragma unroll
        for (int mt = 0; mt < 2; mt++)
#pragma unroll
          for (int r = 0; r < 4; r++) {
            const int prow = mt * 16 + quad * 4 + r;
#pragma unroll
            for (int nt = 0; nt < 4; nt++) {
              float p = __builtin_amdgcn_exp2f(sarr[mt][nt][r]);
              lpart[mt][r] += p;
              plds[wv][prow * 64 + ((nt * 16 + l15) ^ (SW(prow) << 3))] = (__bf16)p;
            }
          }
      } else {
#pragma unroll
        for (int mt = 0; mt < 2; mt++)
#pragma unroll
          for (int r = 0; r < 4; r++) {
            const int prow = mt * 16 + quad * 4 + r;
            const int qglob = qbase + prow;
#pragma unroll
            for (int nt = 0; nt < 4; nt++) {
              const int kglob = t * 64 + nt * 16 + l15;
              float p = (kglob <= qglob) ? __builtin_amdgcn_exp2f(sarr[mt][nt][r]) : 0.f;
              lpart[mt][r] += p;
              plds[wv][prow * 64 + ((nt * 16 + l15) ^ (SW(prow) << 3))] = (__bf16)p;
            }
          }
      }
#pragma unroll
      for (int kb = 0; kb < 2; kb++) {
        bf16x8 pa[2];
#pragma unroll
        for (int mt = 0; mt < 2; mt++) {
          const int row = mt * 16 + l15;
          pa[mt] = *(const bf16x8*)(&plds[wv][row * 64 + (((kb * 4 + quad) ^ SW(row)) << 3)]);
        }
#pragma unroll
        for (int dt = 0; dt < 4; dt++) {
          const int rowv = dt * 16 + l15;
          bf16x8 bv = *(const bf16x8*)(vbuf[cur] + rowv * 64 + (((kb * 4 + quad) ^ SW(rowv)) << 3));
#pragma unroll
          for (int mt = 0; mt < 2; mt++)
            acc[mt][dt] = __builtin_amdgcn_mfma_f32_16x16x32_bf16(pa[mt], bv, acc[mt][dt], 0, 0, 0);
        }
      }
    }

    if (t + 1 < tcnt) {
      const int nxt = cur ^ 1;
      *(bf16x8*)(kbuf[nxt] + sr * 64 + ((c8 ^ SW(sr)) << 3))             = kreg[0];
      *(bf16x8*)(kbuf[nxt] + (sr + 32) * 64 + ((c8 ^ SW(sr + 32)) << 3)) = kreg[1];
      *(bf16x8*)(vbuf[nxt] + sr * 64 + ((c8 ^ SW(sr)) << 3))             = vreg[0];
      *(bf16x8*)(vbuf[nxt] + (sr + 32) * 64 + ((c8 ^ SW(sr + 32)) << 3)) = vreg[1];
    }
    __syncthreads();
  }

  // epilogue: row-sum reduce over l15, normalize, write ctx
#pragma unroll
  for (int mt = 0; mt < 2; mt++)
#pragma unroll
    for (int r = 0; r < 4; r++) {
      float l = lpart[mt][r];
      l += __shfl_xor(l, 1, 64);
      l += __shfl_xor(l, 2, 64);
      l += __shfl_xor(l, 4, 64);
      l += __shfl_xor(l, 8, 64);
      const float linv = 1.f / l;
      const int qrow = qbase + mt * 16 + quad * 4 + r;
#pragma unroll
      for (int dt = 0; dt < 4; dt++)
        ctx[((size_t)(b * TSEQ + qrow)) * DMODEL + h * 64 + dt * 16 + l15] =
            (__bf16)(acc[mt][dt][r] * linv);
    }
}

// ---------------- output projection + bias (fp32 out) ----------------
__global__ __launch_bounds__(256) void k_gemm_out(const __bf16* __restrict__ ctx,
    const __bf16* __restrict__ wot, const float* __restrict__ bo,
    float* __restrict__ out) {
  __shared__ __bf16 At[128 * 32];
  __shared__ __bf16 Bl[128 * 32];
  const int bm = blockIdx.y * 128, bn = blockIdx.x * 128;
  f32x4 acc[4][4];
  const f32x4 z = {0.f, 0.f, 0.f, 0.f};
#pragma unroll
  for (int mt = 0; mt < 4; mt++)
#pragma unroll
    for (int nt = 0; nt < 4; nt++) acc[mt][nt] = z;
  gemm_mainloop(ctx, wot, bm, bn, At, Bl, acc);
  const int lane = threadIdx.x & 63;
  const int l15 = lane & 15, quad = lane >> 4;
  const int wv = threadIdx.x >> 6;
  const int wm = (wv >> 1) * 64, wn = (wv & 1) * 64;
#pragma unroll
  for (int mt = 0; mt < 4; mt++)
#pragma unroll
    for (int nt = 0; nt < 4; nt++)
#pragma unroll
      for (int r = 0; r < 4; r++) {
        int m = bm + wm + mt * 16 + quad * 4 + r;
        int n = bn + wn + nt * 16 + l15;
        out[(size_t)m * DMODEL + n] = acc[mt][nt][r] + bo[n];
      }
}

extern "C" void kernel_launch(void* const* d_in, const int* in_sizes, int n_in,
                              void* d_out, int out_size, void* d_ws, size_t ws_size,
                              hipStream_t stream) {
  const float* x  = (const float*)d_in[0];
  const float* Wq = (const float*)d_in[1];
  const float* Wk = (const float*)d_in[2];
  const float* Wv = (const float*)d_in[3];
  const float* Wo = (const float*)d_in[4];
  const float* bo = (const float*)d_in[5];
  float* out = (float*)d_out;

  __bf16* xbf  = (__bf16*)d_ws;                       // 4096*1024
  __bf16* wt   = xbf  + (size_t)4096 * 1024;          // 4 * 1024*1024
  __bf16* qws  = wt   + (size_t)4 * 1024 * 1024;      // [32][2048][64]
  __bf16* kws  = qws  + (size_t)32 * 2048 * 64;
  __bf16* vtws = kws  + (size_t)32 * 2048 * 64;       // [32][64][VSTRIDE]
  __bf16* ctx  = xbf;                                 // aliases xbf (dead after QKV)

  k_prep<<<8192, 256, 0, stream>>>(x, Wq, Wk, Wv, Wo, xbf, wt);
  k_gemm_qkv<<<dim3(8, 32, 3), 256, 0, stream>>>(xbf, wt, qws, kws, vtws);
  k_attn<<<512, 256, 0, stream>>>(qws, kws, vtws, ctx);
  k_gemm_out<<<dim3(8, 32), 256, 0, stream>>>(ctx, wt + (size_t)3 * 1024 * 1024, bo, out);
}

// Round 2
// 200.137 us; speedup vs baseline: 1.0091x; 1.0091x over previous
//
#include <hip/hip_runtime.h>

typedef __attribute__((ext_vector_type(8))) __bf16 bf16x8;
typedef __attribute__((ext_vector_type(4))) __bf16 bf16x4;
typedef __attribute__((ext_vector_type(4))) float  f32x4;

static constexpr int TSEQ    = 2048;
static constexpr int DMODEL  = 1024;
static constexpr int HD      = 64;
static constexpr int VSTRIDE = 2080;   // V^T row stride (breaks 4KB L2-channel aliasing)

#define AS1 __attribute__((address_space(1)))
#define AS3 __attribute__((address_space(3)))
// XOR bank swizzle on 16B chunks within a 128B row.
// SW>>1 = row bits [3:2]  -> rows {r,r+4,r+8,r+12} (the 4 quads of a P-store) land on
// DISTINCT 32B chunk-pairs (conflict-free b16 scatter); SW repeats only 2x over any 16
// consecutive rows -> K/V b128 fragment reads stay at the 2-way-free spread.
#define SW(r) ((((r) & 12) >> 1) | ((r) & 1))

// ---------------- fused preprocessing: convert x + transpose weights ----------------
__global__ __launch_bounds__(256) void k_prep(const float* __restrict__ x,
    const float* __restrict__ w0, const float* __restrict__ w1,
    const float* __restrict__ w2, const float* __restrict__ w3,
    __bf16* __restrict__ xbf, __bf16* __restrict__ wt_all) {
  __shared__ float tile[32][33];
  const int blk = blockIdx.x;
  const int tid = threadIdx.x;
  if (blk < 4096) {
    size_t i = ((size_t)blk * 256 + tid) * 4;
    float4 v = *(const float4*)(x + i);
    bf16x4 o = { (__bf16)v.x, (__bf16)v.y, (__bf16)v.z, (__bf16)v.w };
    *(bf16x4*)(xbf + i) = o;
    return;
  }
  const int tz = blk - 4096;
  const int wi = tz >> 10;                 // which weight
  const int tl = tz & 1023;
  const int n0 = (tl & 31) * 32, k0 = (tl >> 5) * 32;
  const float* w = wi == 0 ? w0 : wi == 1 ? w1 : wi == 2 ? w2 : w3;
  __bf16* out = wt_all + (size_t)wi * DMODEL * DMODEL;
  const int tx = tid & 31, ty0 = (tid >> 5) * 4;
#pragma unroll
  for (int j = 0; j < 4; j++)
    tile[ty0 + j][tx] = w[(size_t)(k0 + ty0 + j) * DMODEL + n0 + tx];
  __syncthreads();
#pragma unroll
  for (int j = 0; j < 4; j++)
    out[(size_t)(n0 + ty0 + j) * DMODEL + k0 + tx] = (__bf16)tile[tx][ty0 + j];
}

// ---------------- m97-style GEMM mainloop (R6): global_load_lds width-16, BK=32 ----------------
__device__ __forceinline__ void gemm_mainloop(const __bf16* __restrict__ A,
                                              const __bf16* __restrict__ Bt,
                                              int bm, int bn,
                                              __bf16* At, __bf16* Bl,
                                              f32x4 acc[4][4]) {
  const int tid  = threadIdx.x;
  const int lane = tid & 63;
  const int l15  = lane & 15, quad = lane >> 4;
  const int wv   = tid >> 6;
  const int wm   = (wv >> 1) * 64, wn = (wv & 1) * 64;
  const int s0   = wv * 2;
  const int srow = lane >> 2;
  const int scol = (lane & 3) << 3;
  for (int k0 = 0; k0 < 1024; k0 += 32) {
    __syncthreads();
#pragma unroll
    for (int ss = 0; ss < 2; ss++) {
      const int s   = s0 + ss;
      const int row = s * 16 + srow;
      const __bf16* ga = A  + (size_t)(bm + row) * 1024 + k0 + scol;
      const __bf16* gb = Bt + (size_t)(bn + row) * 1024 + k0 + scol;
      __builtin_amdgcn_global_load_lds((const AS1 void*)ga,
                                       (AS3 void*)(At + s * 512), 16, 0, 0);
      __builtin_amdgcn_global_load_lds((const AS1 void*)gb,
                                       (AS3 void*)(Bl + s * 512), 16, 0, 0);
    }
    __syncthreads();
    bf16x8 af[4], bfr[4];
#pragma unroll
    for (int mt = 0; mt < 4; mt++)
      af[mt] = *(const bf16x8*)(At + (wm + mt * 16 + l15) * 32 + quad * 8);
#pragma unroll
    for (int nt = 0; nt < 4; nt++)
      bfr[nt] = *(const bf16x8*)(Bl + (wn + nt * 16 + l15) * 32 + quad * 8);
#pragma unroll
    for (int mt = 0; mt < 4; mt++)
#pragma unroll
      for (int nt = 0; nt < 4; nt++)
        acc[mt][nt] = __builtin_amdgcn_mfma_f32_16x16x32_bf16(
            af[mt], bfr[nt], acc[mt][nt], 0, 0, 0);
  }
}

// ---------------- QKV projection (Q pre-scaled by log2e/8; V stored transposed) ----------------
__global__ __launch_bounds__(256) void k_gemm_qkv(const __bf16* __restrict__ xbf,
    const __bf16* __restrict__ wt_all, __bf16* __restrict__ qws,
    __bf16* __restrict__ kws, __bf16* __restrict__ vtws) {
  __shared__ __bf16 At[128 * 32];
  __shared__ __bf16 Bl[128 * 32];
  const int which = blockIdx.z;
  const __bf16* wt = wt_all + (size_t)which * DMODEL * DMODEL;
  const int bm = blockIdx.y * 128, bn = blockIdx.x * 128;
  f32x4 acc[4][4];
  const f32x4 z = {0.f, 0.f, 0.f, 0.f};
#pragma unroll
  for (int mt = 0; mt < 4; mt++)
#pragma unroll
    for (int nt = 0; nt < 4; nt++) acc[mt][nt] = z;
  gemm_mainloop(xbf, wt, bm, bn, At, Bl, acc);
  const int lane = threadIdx.x & 63;
  const int l15 = lane & 15, quad = lane >> 4;
  const int wv = threadIdx.x >> 6;
  const int wm = (wv >> 1) * 64, wn = (wv & 1) * 64;
#pragma unroll
  for (int mt = 0; mt < 4; mt++)
#pragma unroll
    for (int nt = 0; nt < 4; nt++)
#pragma unroll
      for (int r = 0; r < 4; r++) {
        int m = bm + wm + mt * 16 + quad * 4 + r;
        int n = bn + wn + nt * 16 + l15;
        int b = m >> 11, t = m & 2047;
        int h = n >> 6,  d = n & 63;
        int bh = b * 16 + h;
        float av = acc[mt][nt][r];
        // 0.125 * log2(e): lets attention use v_exp_f32 (exp2) directly
        if (which == 0)      qws[((size_t)bh * TSEQ + t) * HD + d] = (__bf16)(av * 0.18033688f);
        else if (which == 1) kws[((size_t)bh * TSEQ + t) * HD + d] = (__bf16)av;
        else                 vtws[((size_t)bh * HD + d) * VSTRIDE + t] = (__bf16)av;
      }
}

// ---------------- flash attention (R8): R7 structure + LPT dispatch + fixed P-swizzle ----
// grid 512: bh = blk & 31 (XCD locality: 4 bh/XCD => 2MB K+V L2-resident).
// LPT: a = 15 - (blk>>5)  -> the 32-step blocks (a=15) dispatch FIRST across all CUs,
// short blocks backfill.  Makespan ~ 34 steps/CU (total 8704 steps / 256 CUs) instead of
// R7's ~50+ (short-first order serialized the long tail at 1 block/CU).
__global__ __launch_bounds__(256) void k_attn(const __bf16* __restrict__ qws,
    const __bf16* __restrict__ kws, const __bf16* __restrict__ vtws,
    __bf16* __restrict__ ctx) {
  const int bh = blockIdx.x & 31;
  const int a  = 15 - (blockIdx.x >> 5);               // stream index 15..0, longest first
  const int tcnt = 2 * a + 2;                          // causal K-tile count
  const int tid = threadIdx.x;
  const int lane = tid & 63, wv = tid >> 6;
  const int l15 = lane & 15, quad = lane >> 4;
  const __bf16* qp = qws  + (size_t)bh * TSEQ * HD;
  const __bf16* kp = kws  + (size_t)bh * TSEQ * HD;
  const __bf16* vp = vtws + (size_t)bh * HD * VSTRIDE;
  const int b = bh >> 4, h = bh & 15;
  const int qbase = a * 128 + wv * 32;                 // this wave's first q-row

  __shared__ __align__(16) __bf16 kbuf[2][64 * 64];
  __shared__ __align__(16) __bf16 vbuf[2][64 * 64];
  __shared__ __align__(16) __bf16 plds[4][32 * 64];

  const int sr = tid >> 3;        // staging row 0..31
  const int c8 = tid & 7;         // staging 16B chunk

  // Q fragments: 32 rows per wave = 2 m-tiles, K=64 feat = 2 kb chunks
  bf16x8 aq[2][2];
#pragma unroll
  for (int mt = 0; mt < 2; mt++)
#pragma unroll
    for (int kb = 0; kb < 2; kb++)
      aq[mt][kb] = *(const bf16x8*)(qp + (size_t)(qbase + mt * 16 + l15) * HD + kb * 32 + quad * 8);

  // stage tile 0 (swizzled reg->LDS)
  bf16x8 kreg[2], vreg[2];
  kreg[0] = *(const bf16x8*)(kp + (size_t)sr * HD + c8 * 8);
  kreg[1] = *(const bf16x8*)(kp + (size_t)(sr + 32) * HD + c8 * 8);
  vreg[0] = *(const bf16x8*)(vp + (size_t)sr * VSTRIDE + c8 * 8);
  vreg[1] = *(const bf16x8*)(vp + (size_t)(sr + 32) * VSTRIDE + c8 * 8);
  *(bf16x8*)(kbuf[0] + sr * 64 + ((c8 ^ SW(sr)) << 3))             = kreg[0];
  *(bf16x8*)(kbuf[0] + (sr + 32) * 64 + ((c8 ^ SW(sr + 32)) << 3)) = kreg[1];
  *(bf16x8*)(vbuf[0] + sr * 64 + ((c8 ^ SW(sr)) << 3))             = vreg[0];
  *(bf16x8*)(vbuf[0] + (sr + 32) * 64 + ((c8 ^ SW(sr + 32)) << 3)) = vreg[1];
  __syncthreads();

  float lpart[2][4] = {{0.f, 0.f, 0.f, 0.f}, {0.f, 0.f, 0.f, 0.f}};
  const f32x4 z = {0.f, 0.f, 0.f, 0.f};
  f32x4 acc[2][4];
#pragma unroll
  for (int mt = 0; mt < 2; mt++)
#pragma unroll
    for (int dt = 0; dt < 4; dt++) acc[mt][dt] = z;

  for (int t = 0; t < tcnt; t++) {
    const int cur = t & 1;
    if (t + 1 < tcnt) {                       // prefetch next tile into regs (hidden under compute)
      const int ktn = (t + 1) * 64;
      kreg[0] = *(const bf16x8*)(kp + (size_t)(ktn + sr) * HD + c8 * 8);
      kreg[1] = *(const bf16x8*)(kp + (size_t)(ktn + sr + 32) * HD + c8 * 8);
      vreg[0] = *(const bf16x8*)(vp + (size_t)sr * VSTRIDE + ktn + c8 * 8);
      vreg[1] = *(const bf16x8*)(vp + (size_t)(sr + 32) * VSTRIDE + ktn + c8 * 8);
    }

    const bool skipall = (t * 64) > (qbase + 31);     // wave fully above causal boundary
    if (!skipall) {
      const bool full = (t * 64 + 63) <= qbase;       // wave fully unmasked (wave-uniform)
      f32x4 sarr[2][4];
#pragma unroll
      for (int mt = 0; mt < 2; mt++)
#pragma unroll
        for (int nt = 0; nt < 4; nt++) sarr[mt][nt] = z;
#pragma unroll
      for (int kb = 0; kb < 2; kb++)
#pragma unroll
        for (int nt = 0; nt < 4; nt++) {
          const int row = nt * 16 + l15;
          bf16x8 bk = *(const bf16x8*)(kbuf[cur] + row * 64 + (((kb * 4 + quad) ^ SW(row)) << 3));
#pragma unroll
          for (int mt = 0; mt < 2; mt++)
            sarr[mt][nt] = __builtin_amdgcn_mfma_f32_16x16x32_bf16(aq[mt][kb], bk, sarr[mt][nt], 0, 0, 0);
        }
      if (full) {
#pragma unroll
        for (int mt = 0; mt < 2; mt++)
#pragma unroll
          for (int r = 0; r < 4; r++) {
            const int prow = mt * 16 + quad * 4 + r;
#pragma unroll
            for (int nt = 0; nt < 4; nt++) {
              float p = __builtin_amdgcn_exp2f(sarr[mt][nt][r]);
              lpart[mt][r] += p;
              plds[wv][prow * 64 + ((nt * 16 + l15) ^ (SW(prow) << 3))] = (__bf16)p;
            }
          }
      } else {
#pragma unroll
        for (int mt = 0; mt < 2; mt++)
#pragma unroll
          for (int r = 0; r < 4; r++) {
            const int prow = mt * 16 + quad * 4 + r;
            const int qglob = qbase + prow;
#pragma unroll
            for (int nt = 0; nt < 4; nt++) {
              const int kglob = t * 64 + nt * 16 + l15;
              float p = (kglob <= qglob) ? __builtin_amdgcn_exp2f(sarr[mt][nt][r]) : 0.f;
              lpart[mt][r] += p;
              plds[wv][prow * 64 + ((nt * 16 + l15) ^ (SW(prow) << 3))] = (__bf16)p;
            }
          }
      }
#pragma unroll
      for (int kb = 0; kb < 2; kb++) {
        bf16x8 pa[2];
#pragma unroll
        for (int mt = 0; mt < 2; mt++) {
          const int row = mt * 16 + l15;
          pa[mt] = *(const bf16x8*)(&plds[wv][row * 64 + (((kb * 4 + quad) ^ SW(row)) << 3)]);
        }
#pragma unroll
        for (int dt = 0; dt < 4; dt++) {
          const int rowv = dt * 16 + l15;
          bf16x8 bv = *(const bf16x8*)(vbuf[cur] + rowv * 64 + (((kb * 4 + quad) ^ SW(rowv)) << 3));
#pragma unroll
          for (int mt = 0; mt < 2; mt++)
            acc[mt][dt] = __builtin_amdgcn_mfma_f32_16x16x32_bf16(pa[mt], bv, acc[mt][dt], 0, 0, 0);
        }
      }
    }

    if (t + 1 < tcnt) {
      const int nxt = cur ^ 1;
      *(bf16x8*)(kbuf[nxt] + sr * 64 + ((c8 ^ SW(sr)) << 3))             = kreg[0];
      *(bf16x8*)(kbuf[nxt] + (sr + 32) * 64 + ((c8 ^ SW(sr + 32)) << 3)) = kreg[1];
      *(bf16x8*)(vbuf[nxt] + sr * 64 + ((c8 ^ SW(sr)) << 3))             = vreg[0];
      *(bf16x8*)(vbuf[nxt] + (sr + 32) * 64 + ((c8 ^ SW(sr + 32)) << 3)) = vreg[1];
    }
    __syncthreads();
  }

  // epilogue: row-sum reduce over l15, normalize, write ctx
#pragma unroll
  for (int mt = 0; mt < 2; mt++)
#pragma unroll
    for (int r = 0; r < 4; r++) {
      float l = lpart[mt][r];
      l += __shfl_xor(l, 1, 64);
      l += __shfl_xor(l, 2, 64);
      l += __shfl_xor(l, 4, 64);
      l += __shfl_xor(l, 8, 64);
      const float linv = 1.f / l;
      const int qrow = qbase + mt * 16 + quad * 4 + r;
#pragma unroll
      for (int dt = 0; dt < 4; dt++)
        ctx[((size_t)(b * TSEQ + qrow)) * DMODEL + h * 64 + dt * 16 + l15] =
            (__bf16)(acc[mt][dt][r] * linv);
    }
}

// ---------------- output projection + bias (fp32 out) ----------------
__global__ __launch_bounds__(256) void k_gemm_out(const __bf16* __restrict__ ctx,
    const __bf16* __restrict__ wot, const float* __restrict__ bo,
    float* __restrict__ out) {
  __shared__ __bf16 At[128 * 32];
  __shared__ __bf16 Bl[128 * 32];
  const int bm = blockIdx.y * 128, bn = blockIdx.x * 128;
  f32x4 acc[4][4];
  const f32x4 z = {0.f, 0.f, 0.f, 0.f};
#pragma unroll
  for (int mt = 0; mt < 4; mt++)
#pragma unroll
    for (int nt = 0; nt < 4; nt++) acc[mt][nt] = z;
  gemm_mainloop(ctx, wot, bm, bn, At, Bl, acc);
  const int lane = threadIdx.x & 63;
  const int l15 = lane & 15, quad = lane >> 4;
  const int wv = threadIdx.x >> 6;
  const int wm = (wv >> 1) * 64, wn = (wv & 1) * 64;
#pragma unroll
  for (int mt = 0; mt < 4; mt++)
#pragma unroll
    for (int nt = 0; nt < 4; nt++)
#pragma unroll
      for (int r = 0; r < 4; r++) {
        int m = bm + wm + mt * 16 + quad * 4 + r;
        int n = bn + wn + nt * 16 + l15;
        out[(size_t)m * DMODEL + n] = acc[mt][nt][r] + bo[n];
      }
}

extern "C" void kernel_launch(void* const* d_in, const int* in_sizes, int n_in,
                              void* d_out, int out_size, void* d_ws, size_t ws_size,
                              hipStream_t stream) {
  const float* x  = (const float*)d_in[0];
  const float* Wq = (const float*)d_in[1];
  const float* Wk = (const float*)d_in[2];
  const float* Wv = (const float*)d_in[3];
  const float* Wo = (const float*)d_in[4];
  const float* bo = (const float*)d_in[5];
  float* out = (float*)d_out;

  __bf16* xbf  = (__bf16*)d_ws;                       // 4096*1024
  __bf16* wt   = xbf  + (size_t)4096 * 1024;          // 4 * 1024*1024
  __bf16* qws  = wt   + (size_t)4 * 1024 * 1024;      // [32][2048][64]
  __bf16* kws  = qws  + (size_t)32 * 2048 * 64;
  __bf16* vtws = kws  + (size_t)32 * 2048 * 64;       // [32][64][VSTRIDE]
  __bf16* ctx  = xbf;                                 // aliases xbf (dead after QKV)

  k_prep<<<8192, 256, 0, stream>>>(x, Wq, Wk, Wv, Wo, xbf, wt);
  k_gemm_qkv<<<dim3(8, 32, 3), 256, 0, stream>>>(xbf, wt, qws, kws, vtws);
  k_attn<<<512, 256, 0, stream>>>(qws, kws, vtws, ctx);
  k_gemm_out<<<dim3(8, 32), 256, 0, stream>>>(ctx, wt + (size_t)3 * 1024 * 1024, bo, out);
}

// Round 3
// 195.401 us; speedup vs baseline: 1.0336x; 1.0242x over previous
//
#include <hip/hip_runtime.h>

typedef __attribute__((ext_vector_type(8)))  __bf16 bf16x8;
typedef __attribute__((ext_vector_type(4)))  __bf16 bf16x4;
typedef __attribute__((ext_vector_type(4)))  float  f32x4;
typedef __attribute__((ext_vector_type(16))) float  f32x16;
typedef __attribute__((ext_vector_type(4)))  int    i32x4;

static constexpr int TSEQ    = 2048;
static constexpr int DMODEL  = 1024;
static constexpr int HD      = 64;
static constexpr int VSTRIDE = 2080;   // V^T row stride (breaks 4KB L2-channel aliasing)

#define AS1 __attribute__((address_space(1)))
#define AS3 __attribute__((address_space(3)))
// XOR bank swizzle on 16B chunks within a 128B row. Each SW value is shared by 4 rows in
// any 32-row window; combined with the hi-bit phase this spreads every b128 wave-access
// exactly 8 lanes/chunk = the conflict-free floor.
#define SW(r) ((((r) & 12) >> 1) | ((r) & 1))

// ---------------- fused preprocessing: convert x + transpose weights ----------------
__global__ __launch_bounds__(256) void k_prep(const float* __restrict__ x,
    const float* __restrict__ w0, const float* __restrict__ w1,
    const float* __restrict__ w2, const float* __restrict__ w3,
    __bf16* __restrict__ xbf, __bf16* __restrict__ wt_all) {
  __shared__ float tile[32][33];
  const int blk = blockIdx.x;
  const int tid = threadIdx.x;
  if (blk < 4096) {
    size_t i = ((size_t)blk * 256 + tid) * 4;
    float4 v = *(const float4*)(x + i);
    bf16x4 o = { (__bf16)v.x, (__bf16)v.y, (__bf16)v.z, (__bf16)v.w };
    *(bf16x4*)(xbf + i) = o;
    return;
  }
  const int tz = blk - 4096;
  const int wi = tz >> 10;                 // which weight
  const int tl = tz & 1023;
  const int n0 = (tl & 31) * 32, k0 = (tl >> 5) * 32;
  const float* w = wi == 0 ? w0 : wi == 1 ? w1 : wi == 2 ? w2 : w3;
  __bf16* out = wt_all + (size_t)wi * DMODEL * DMODEL;
  const int tx = tid & 31, ty0 = (tid >> 5) * 4;
#pragma unroll
  for (int j = 0; j < 4; j++)
    tile[ty0 + j][tx] = w[(size_t)(k0 + ty0 + j) * DMODEL + n0 + tx];
  __syncthreads();
#pragma unroll
  for (int j = 0; j < 4; j++)
    out[(size_t)(n0 + ty0 + j) * DMODEL + k0 + tx] = (__bf16)tile[tx][ty0 + j];
}

// ---------------- m97-style GEMM mainloop (R6): global_load_lds width-16, BK=32 ----------------
__device__ __forceinline__ void gemm_mainloop(const __bf16* __restrict__ A,
                                              const __bf16* __restrict__ Bt,
                                              int bm, int bn,
                                              __bf16* At, __bf16* Bl,
                                              f32x4 acc[4][4]) {
  const int tid  = threadIdx.x;
  const int lane = tid & 63;
  const int l15  = lane & 15, quad = lane >> 4;
  const int wv   = tid >> 6;
  const int wm   = (wv >> 1) * 64, wn = (wv & 1) * 64;
  const int s0   = wv * 2;
  const int srow = lane >> 2;
  const int scol = (lane & 3) << 3;
  for (int k0 = 0; k0 < 1024; k0 += 32) {
    __syncthreads();
#pragma unroll
    for (int ss = 0; ss < 2; ss++) {
      const int s   = s0 + ss;
      const int row = s * 16 + srow;
      const __bf16* ga = A  + (size_t)(bm + row) * 1024 + k0 + scol;
      const __bf16* gb = Bt + (size_t)(bn + row) * 1024 + k0 + scol;
      __builtin_amdgcn_global_load_lds((const AS1 void*)ga,
                                       (AS3 void*)(At + s * 512), 16, 0, 0);
      __builtin_amdgcn_global_load_lds((const AS1 void*)gb,
                                       (AS3 void*)(Bl + s * 512), 16, 0, 0);
    }
    __syncthreads();
    bf16x8 af[4], bfr[4];
#pragma unroll
    for (int mt = 0; mt < 4; mt++)
      af[mt] = *(const bf16x8*)(At + (wm + mt * 16 + l15) * 32 + quad * 8);
#pragma unroll
    for (int nt = 0; nt < 4; nt++)
      bfr[nt] = *(const bf16x8*)(Bl + (wn + nt * 16 + l15) * 32 + quad * 8);
#pragma unroll
    for (int mt = 0; mt < 4; mt++)
#pragma unroll
      for (int nt = 0; nt < 4; nt++)
        acc[mt][nt] = __builtin_amdgcn_mfma_f32_16x16x32_bf16(
            af[mt], bfr[nt], acc[mt][nt], 0, 0, 0);
  }
}

// ---------------- QKV projection (Q pre-scaled by log2e/8; V stored transposed) ----------------
__global__ __launch_bounds__(256) void k_gemm_qkv(const __bf16* __restrict__ xbf,
    const __bf16* __restrict__ wt_all, __bf16* __restrict__ qws,
    __bf16* __restrict__ kws, __bf16* __restrict__ vtws) {
  __shared__ __bf16 At[128 * 32];
  __shared__ __bf16 Bl[128 * 32];
  const int which = blockIdx.z;
  const __bf16* wt = wt_all + (size_t)which * DMODEL * DMODEL;
  const int bm = blockIdx.y * 128, bn = blockIdx.x * 128;
  f32x4 acc[4][4];
  const f32x4 z = {0.f, 0.f, 0.f, 0.f};
#pragma unroll
  for (int mt = 0; mt < 4; mt++)
#pragma unroll
    for (int nt = 0; nt < 4; nt++) acc[mt][nt] = z;
  gemm_mainloop(xbf, wt, bm, bn, At, Bl, acc);
  const int lane = threadIdx.x & 63;
  const int l15 = lane & 15, quad = lane >> 4;
  const int wv = threadIdx.x >> 6;
  const int wm = (wv >> 1) * 64, wn = (wv & 1) * 64;
#pragma unroll
  for (int mt = 0; mt < 4; mt++)
#pragma unroll
    for (int nt = 0; nt < 4; nt++)
#pragma unroll
      for (int r = 0; r < 4; r++) {
        int m = bm + wm + mt * 16 + quad * 4 + r;
        int n = bn + wn + nt * 16 + l15;
        int b = m >> 11, t = m & 2047;
        int h = n >> 6,  d = n & 63;
        int bh = b * 16 + h;
        float av = acc[mt][nt][r];
        // 0.125 * log2(e): lets attention use v_exp_f32 (exp2) directly
        if (which == 0)      qws[((size_t)bh * TSEQ + t) * HD + d] = (__bf16)(av * 0.18033688f);
        else if (which == 1) kws[((size_t)bh * TSEQ + t) * HD + d] = (__bf16)av;
        else                 vtws[((size_t)bh * HD + d) * VSTRIDE + t] = (__bf16)av;
      }
}

// ---------------- flash attention (R9): 32x32 MFMA, swapped QK^T, in-register softmax ----
// No P LDS roundtrip: S^T = mfma32(K, Q) puts P[q=lane&31][k-in-regs]; cvt_pk_bf16 +
// cross-half word exchange (shfl_xor 32) builds the PV A-fragment directly in VGPRs.
// LDS = 32KB (K/V dbuf only) -> 4 blocks/CU. CU pair (c, c+256) sums to uniform 34 steps.
__global__ __launch_bounds__(256) void k_attn(const __bf16* __restrict__ qws,
    const __bf16* __restrict__ kws, const __bf16* __restrict__ vtws,
    __bf16* __restrict__ ctx) {
  const int bh = blockIdx.x & 31;
  const int tr = blockIdx.x >> 5;
  const int a  = (tr < 8) ? (15 - tr) : (tr - 8);    // pair (c, c+256): (15-t)+(t) = 15
  const int tcnt = 2 * a + 2;                        // causal K-tile count
  const int tid = threadIdx.x;
  const int lane = tid & 63, wv = tid >> 6;
  const int l31 = lane & 31, hi = lane >> 5;
  const __bf16* qp = qws  + (size_t)bh * TSEQ * HD;
  const __bf16* kp = kws  + (size_t)bh * TSEQ * HD;
  const __bf16* vp = vtws + (size_t)bh * HD * VSTRIDE;
  const int b = bh >> 4, h = bh & 15;
  const int qbase = a * 128 + wv * 32;               // this wave's 32 q-rows
  const int qg    = qbase + l31;                     // this lane's q-row

  __shared__ __align__(16) __bf16 kbuf[2][64 * 64];
  __shared__ __align__(16) __bf16 vbuf[2][64 * 64];

  const int sr = tid >> 3;        // staging row 0..31
  const int c8 = tid & 7;         // staging 16B chunk

  // Q fragments (B-operand of swapped QK): lane q=l31 holds d = s*16 + hi*8 + j
  bf16x8 aq[4];
#pragma unroll
  for (int s = 0; s < 4; s++)
    aq[s] = *(const bf16x8*)(qp + (size_t)qg * HD + s * 16 + hi * 8);

  // stage tile 0 (swizzled reg->LDS)
  bf16x8 kreg[2], vreg[2];
  kreg[0] = *(const bf16x8*)(kp + (size_t)sr * HD + c8 * 8);
  kreg[1] = *(const bf16x8*)(kp + (size_t)(sr + 32) * HD + c8 * 8);
  vreg[0] = *(const bf16x8*)(vp + (size_t)sr * VSTRIDE + c8 * 8);
  vreg[1] = *(const bf16x8*)(vp + (size_t)(sr + 32) * VSTRIDE + c8 * 8);
  *(bf16x8*)(kbuf[0] + sr * 64 + ((c8 ^ SW(sr)) << 3))             = kreg[0];
  *(bf16x8*)(kbuf[0] + (sr + 32) * 64 + ((c8 ^ SW(sr + 32)) << 3)) = kreg[1];
  *(bf16x8*)(vbuf[0] + sr * 64 + ((c8 ^ SW(sr)) << 3))             = vreg[0];
  *(bf16x8*)(vbuf[0] + (sr + 32) * 64 + ((c8 ^ SW(sr + 32)) << 3)) = vreg[1];
  __syncthreads();

  const f32x16 z16 = {0.f,0.f,0.f,0.f,0.f,0.f,0.f,0.f,0.f,0.f,0.f,0.f,0.f,0.f,0.f,0.f};
  float lpart = 0.f;                 // lane-local denominator half (q=l31, own k's)
  f32x16 acc[2];
  acc[0] = z16; acc[1] = z16;

  for (int t = 0; t < tcnt; t++) {
    const int cur = t & 1;
    if (t + 1 < tcnt) {                       // prefetch next tile into regs
      const int ktn = (t + 1) * 64;
      kreg[0] = *(const bf16x8*)(kp + (size_t)(ktn + sr) * HD + c8 * 8);
      kreg[1] = *(const bf16x8*)(kp + (size_t)(ktn + sr + 32) * HD + c8 * 8);
      vreg[0] = *(const bf16x8*)(vp + (size_t)sr * VSTRIDE + ktn + c8 * 8);
      vreg[1] = *(const bf16x8*)(vp + (size_t)(sr + 32) * VSTRIDE + ktn + c8 * 8);
    }

    const bool skipall = (t * 64) > (qbase + 31);   // wave fully above causal boundary
    if (!skipall) {
      const bool full = (t * 64 + 63) <= qbase;     // wave fully unmasked (wave-uniform)
      const __bf16* kb_ = kbuf[cur];
      const __bf16* vb_ = vbuf[cur];
#pragma unroll
      for (int kt = 0; kt < 2; kt++) {
        // ---- QK^T swapped: S^T[k][q], k = 32 rows of this kt sub-tile ----
        f32x16 s = z16;
#pragma unroll
        for (int ds = 0; ds < 4; ds++) {
          const int krow = kt * 32 + l31;
          bf16x8 ak = *(const bf16x8*)(kb_ + krow * 64 + (((ds * 2 + hi) ^ SW(krow)) << 3));
          s = __builtin_amdgcn_mfma_f32_32x32x16_bf16(ak, aq[ds], s, 0, 0, 0);
        }
        // ---- softmax numerators in-register (reg r holds k_local = (r&3)+8*(r>>2)+4*hi) ----
        float pv[16];
        if (full) {
#pragma unroll
          for (int r = 0; r < 16; r++) {
            pv[r] = __builtin_amdgcn_exp2f(s[r]);
            lpart += pv[r];
          }
        } else {
#pragma unroll
          for (int r = 0; r < 16; r++) {
            const int kg = t * 64 + kt * 32 + (r & 3) + 8 * (r >> 2) + 4 * hi;
            float p = (kg <= qg) ? __builtin_amdgcn_exp2f(s[r]) : 0.f;
            pv[r] = p;
            lpart += p;
          }
        }
        // ---- pack to bf16 pairs: c0..c7 cover k = {0,1},{2,3},{8,9},{10,11},{16..},{24..} (+4*hi)
        int c[8];
#pragma unroll
        for (int j = 0; j < 8; j++) {
          int w;
          asm("v_cvt_pk_bf16_f32 %0, %1, %2" : "=v"(w) : "v"(pv[2 * j]), "v"(pv[2 * j + 1]));
          c[j] = w;
        }
        // ---- cross-half exchange -> PV A-fragments (lane q=l31, k = hi*8 + j) ----
        const int oc0 = __shfl_xor(c[0], 32, 64), oc1 = __shfl_xor(c[1], 32, 64);
        const int oc2 = __shfl_xor(c[2], 32, 64), oc3 = __shfl_xor(c[3], 32, 64);
        const int oc4 = __shfl_xor(c[4], 32, 64), oc5 = __shfl_xor(c[5], 32, 64);
        const int oc6 = __shfl_xor(c[6], 32, 64), oc7 = __shfl_xor(c[7], 32, 64);
        i32x4 w0 = { hi ? oc2 : c[0], hi ? oc3 : c[1], hi ? c[2] : oc0, hi ? c[3] : oc1 };
        i32x4 w1 = { hi ? oc6 : c[4], hi ? oc7 : c[5], hi ? c[6] : oc4, hi ? c[7] : oc5 };
        bf16x8 pa0 = __builtin_bit_cast(bf16x8, w0);   // k-slice kt*32 + [0,16)
        bf16x8 pa1 = __builtin_bit_cast(bf16x8, w1);   // k-slice kt*32 + [16,32)
        // ---- PV: D[q][d] += P[q][k] * V[k][d]  (B from V^T rows d = lane&31) ----
#pragma unroll
        for (int dt = 0; dt < 2; dt++) {
          const int vrow = dt * 32 + l31;
          bf16x8 bv0 = *(const bf16x8*)(vb_ + vrow * 64 + (((kt * 4 + 0 + hi) ^ SW(vrow)) << 3));
          acc[dt] = __builtin_amdgcn_mfma_f32_32x32x16_bf16(pa0, bv0, acc[dt], 0, 0, 0);
          bf16x8 bv1 = *(const bf16x8*)(vb_ + vrow * 64 + (((kt * 4 + 2 + hi) ^ SW(vrow)) << 3));
          acc[dt] = __builtin_amdgcn_mfma_f32_32x32x16_bf16(pa1, bv1, acc[dt], 0, 0, 0);
        }
      }
    }

    if (t + 1 < tcnt) {
      const int nxt = cur ^ 1;
      *(bf16x8*)(kbuf[nxt] + sr * 64 + ((c8 ^ SW(sr)) << 3))             = kreg[0];
      *(bf16x8*)(kbuf[nxt] + (sr + 32) * 64 + ((c8 ^ SW(sr + 32)) << 3)) = kreg[1];
      *(bf16x8*)(vbuf[nxt] + sr * 64 + ((c8 ^ SW(sr)) << 3))             = vreg[0];
      *(bf16x8*)(vbuf[nxt] + (sr + 32) * 64 + ((c8 ^ SW(sr + 32)) << 3)) = vreg[1];
    }
    __syncthreads();
  }

  // ---- epilogue: full row denominator = own half + partner half; normalize + store ----
  const float lfull = lpart + __shfl_xor(lpart, 32, 64);   // lane x: denom for q = x&31
#pragma unroll
  for (int r = 0; r < 16; r++) {
    const int ql = (r & 3) + 8 * (r >> 2) + 4 * hi;        // output row of acc reg r
    const float linv = 1.f / __shfl(lfull, ql, 64);
    const int qrow = qbase + ql;
#pragma unroll
    for (int dt = 0; dt < 2; dt++)
      ctx[((size_t)(b * TSEQ + qrow)) * DMODEL + h * 64 + dt * 32 + l31] =
          (__bf16)(acc[dt][r] * linv);
  }
}

// ---------------- output projection + bias (fp32 out) ----------------
__global__ __launch_bounds__(256) void k_gemm_out(const __bf16* __restrict__ ctx,
    const __bf16* __restrict__ wot, const float* __restrict__ bo,
    float* __restrict__ out) {
  __shared__ __bf16 At[128 * 32];
  __shared__ __bf16 Bl[128 * 32];
  const int bm = blockIdx.y * 128, bn = blockIdx.x * 128;
  f32x4 acc[4][4];
  const f32x4 z = {0.f, 0.f, 0.f, 0.f};
#pragma unroll
  for (int mt = 0; mt < 4; mt++)
#pragma unroll
    for (int nt = 0; nt < 4; nt++) acc[mt][nt] = z;
  gemm_mainloop(ctx, wot, bm, bn, At, Bl, acc);
  const int lane = threadIdx.x & 63;
  const int l15 = lane & 15, quad = lane >> 4;
  const int wv = threadIdx.x >> 6;
  const int wm = (wv >> 1) * 64, wn = (wv & 1) * 64;
#pragma unroll
  for (int mt = 0; mt < 4; mt++)
#pragma unroll
    for (int nt = 0; nt < 4; nt++)
#pragma unroll
      for (int r = 0; r < 4; r++) {
        int m = bm + wm + mt * 16 + quad * 4 + r;
        int n = bn + wn + nt * 16 + l15;
        out[(size_t)m * DMODEL + n] = acc[mt][nt][r] + bo[n];
      }
}

extern "C" void kernel_launch(void* const* d_in, const int* in_sizes, int n_in,
                              void* d_out, int out_size, void* d_ws, size_t ws_size,
                              hipStream_t stream) {
  const float* x  = (const float*)d_in[0];
  const float* Wq = (const float*)d_in[1];
  const float* Wk = (const float*)d_in[2];
  const float* Wv = (const float*)d_in[3];
  const float* Wo = (const float*)d_in[4];
  const float* bo = (const float*)d_in[5];
  float* out = (float*)d_out;

  __bf16* xbf  = (__bf16*)d_ws;                       // 4096*1024
  __bf16* wt   = xbf  + (size_t)4096 * 1024;          // 4 * 1024*1024
  __bf16* qws  = wt   + (size_t)4 * 1024 * 1024;      // [32][2048][64]
  __bf16* kws  = qws  + (size_t)32 * 2048 * 64;
  __bf16* vtws = kws  + (size_t)32 * 2048 * 64;       // [32][64][VSTRIDE]
  __bf16* ctx  = xbf;                                 // aliases xbf (dead after QKV)

  k_prep<<<8192, 256, 0, stream>>>(x, Wq, Wk, Wv, Wo, xbf, wt);
  k_gemm_qkv<<<dim3(8, 32, 3), 256, 0, stream>>>(xbf, wt, qws, kws, vtws);
  k_attn<<<512, 256, 0, stream>>>(qws, kws, vtws, ctx);
  k_gemm_out<<<dim3(8, 32), 256, 0, stream>>>(ctx, wt + (size_t)3 * 1024 * 1024, bo, out);
}